// Round 10
// baseline (1124.695 us; speedup 1.0000x reference)
//
#include <hip/hip_runtime.h>
#include <hip/hip_bf16.h>

#define N_NODES 10000
#define N_EDGES 160000
#define FEAT_W 320
#define CHUNK 16
#define GT 192   // gather block size: thread t owns columns t and t+192

__device__ __forceinline__ float gelu_tanh(float x) {
    float x3 = x * x * x;
    float t = tanhf(0.7978845608028654f * (x + 0.044715f * x3));
    return 0.5f * x * (1.0f + t);
}

// ---------------- Kernel 1: node transforms, 8 nodes/block ------------------
// feat_tbl / self_tbl rows: [0..128) = mul0 part, [128..320) = mul1 part as u*3+i
__global__ __launch_bounds__(256) void node_transform(
    const float* __restrict__ node_input,
    const float* __restrict__ Wa0, const float* __restrict__ Wa1,
    const float* __restrict__ Wb0, const float* __restrict__ Wb1,
    float* __restrict__ feat_tbl, float* __restrict__ self_tbl)
{
    __shared__ float x[8][FEAT_W];         // 10.24 KB
    const int node0 = blockIdx.x * 8;
    const int t = threadIdx.x;
    for (int q = t; q < 8 * FEAT_W / 4; q += 256)
        ((float4*)x)[q] = ((const float4*)(node_input + (size_t)node0 * FEAT_W))[q];
    __syncthreads();

    for (int g = 0; g < 3; ++g) {
        const int oidx = t + g * 256;
        if (oidx >= 640) break;
        const bool is_self = (oidx >= 320);
        const int idx = is_self ? oidx - 320 : oidx;
        float acc[8] = {0, 0, 0, 0, 0, 0, 0, 0};
        if (idx < 128) {
            const float* W = is_self ? Wb0 : Wa0;
            for (int v = 0; v < 128; ++v) {
                const float wv = W[v * 128 + idx];
#pragma unroll
                for (int n = 0; n < 8; ++n) acc[n] += x[n][v] * wv;
            }
#pragma unroll
            for (int n = 0; n < 8; ++n) acc[n] *= 0.08838834764831845f;  // 1/sqrt(128)
        } else {
            const int r = idx - 128, u = r / 3, i = r - 3 * u;
            const float* W = is_self ? Wb1 : Wa1;
            for (int v = 0; v < 64; ++v) {
                const float wv = W[v * 64 + u];
#pragma unroll
                for (int n = 0; n < 8; ++n) acc[n] += x[n][128 + v * 3 + i] * wv;
            }
#pragma unroll
            for (int n = 0; n < 8; ++n) acc[n] *= 0.125f;                // 1/sqrt(64)
        }
        float* outp = is_self ? self_tbl : feat_tbl;
#pragma unroll
        for (int n = 0; n < 8; ++n)
            outp[(size_t)(node0 + n) * FEAT_W + idx] = acc[n];
    }
}

// ---------------- Kernel 2: per-edge MLP -> h2 ------------------------------
__global__ __launch_bounds__(256) void mlp_kernel(
    const float* __restrict__ esa,   // (E,8)
    const float* __restrict__ M1,    // (8,64)
    const float* __restrict__ M2,    // (64,64)
    float* __restrict__ h2buf)       // (E,64)
{
    __shared__ float sh[4][64];
    const int wave = threadIdx.x >> 6;
    const int lane = threadIdx.x & 63;
    const int e = blockIdx.x * 4 + wave;   // N_EDGES % 4 == 0

    const float* er = esa + (size_t)e * 8;
    float h = 0.f;
#pragma unroll
    for (int k = 0; k < 8; ++k) h += er[k] * M1[k * 64 + lane];
    h = gelu_tanh(h * 0.35355339059327373f);   // 1/sqrt(8)
    sh[wave][lane] = h;
    __syncthreads();

    float h2 = 0.f;
    for (int v = 0; v < 64; ++v) h2 += sh[wave][v] * M2[v * 64 + lane];
    h2 = gelu_tanh(h2 * 0.125f);               // 1/sqrt(64)
    h2buf[(size_t)e * 64 + lane] = h2;
}

// ---------------- CSR build -------------------------------------------------
__global__ void count_kernel(const int* __restrict__ edge_dst, int* __restrict__ counts) {
    int e = blockIdx.x * 256 + threadIdx.x;
    if (e < N_EDGES) atomicAdd(&counts[edge_dst[e]], 1);
}

__global__ __launch_bounds__(1024) void scan_kernel(
    const int* __restrict__ counts, int* __restrict__ offsets, int* __restrict__ cursor)
{
    __shared__ int buf[1024];
    int base = 0;
    for (int c = 0; c < 10; ++c) {            // 10*1024 >= 10000
        int i = c * 1024 + threadIdx.x;
        int v = (i < N_NODES) ? counts[i] : 0;
        buf[threadIdx.x] = v;
        __syncthreads();
        for (int off = 1; off < 1024; off <<= 1) {
            int t = (threadIdx.x >= off) ? buf[threadIdx.x - off] : 0;
            __syncthreads();
            buf[threadIdx.x] += t;
            __syncthreads();
        }
        int excl = buf[threadIdx.x] - v;
        if (i < N_NODES) { offsets[i] = base + excl; cursor[i] = base + excl; }
        int tot = buf[1023];
        __syncthreads();
        base += tot;
    }
    if (threadIdx.x == 0) offsets[N_NODES] = base;
}

__global__ void fill_kernel(const int* __restrict__ edge_dst,
                            int* __restrict__ cursor, int* __restrict__ elist) {
    int e = blockIdx.x * 256 + threadIdx.x;
    if (e < N_EDGES) {
        int pos = atomicAdd(&cursor[edge_dst[e]], 1);
        elist[pos] = e;
    }
}

// ---------------- Kernel 3: fused gather: proj + TP + out-GEMM --------------
// 192 threads/block, one block per node. Thread t owns TWO weight columns:
//   c0 = t:       t<128 -> Wtp0 col t (kind A);  t in [128,192) -> Wtp1 col t-128 (kind B)
//   c1 = t+192:   t<64  -> Wtp1 col t+64 (B); t in [64,128) -> Wtp2 col t-64 (C);
//                 t>=128 -> Wtp3 col t-128 (D)
// Each ds_read_b128 of h2 feeds 8 FMAs (2 cols) -> half of R9's LDS traffic at
// half the threads. Weights read from global per q (L1/L2-hot). Every thread
// has exactly 4 accumulators. z layout: [0,192)=z0; [192+i*192+v)=z1[v][i].
__global__ __launch_bounds__(GT) void gather_kernel(
    const int* __restrict__ offsets, const int* __restrict__ elist,
    const int* __restrict__ edge_src,
    const float* __restrict__ edge_attr,   // (E,4)
    const float* __restrict__ h2buf,       // (E,64)
    const float* __restrict__ feat_tbl,    // (N,320)
    const float* __restrict__ self_tbl,    // (N,320)
    const float* __restrict__ Wtp0,        // (64,128)
    const float* __restrict__ Wtp1,        // (64,128)
    const float* __restrict__ Wtp2,        // (64,64)
    const float* __restrict__ Wtp3,        // (64,64)
    const float* __restrict__ Wo0,         // (192,128)
    const float* __restrict__ Wo1,         // (192,64)
    float* __restrict__ out)               // (N,320)
{
    __shared__ __align__(16) float h2s[CHUNK * 68];  // 4.25 KB
    __shared__ float ys[CHUNK][4];
    __shared__ int   eids[CHUNK];
    __shared__ int   srcs[CHUNK];
    __shared__ float z[768];                         // 3 KB

    const int node = blockIdx.x;
    const int t = threadIdx.x;             // 0..191

    // ---- weight column pointers (global; L1/L2-hot, reloaded per q) ----
    const float* wp0; int ws0;
    if (t < 128) { wp0 = Wtp0 + t;         ws0 = 128; }
    else         { wp0 = Wtp1 + (t - 128); ws0 = 128; }
    const float* wp1; int ws1;
    if (t < 64)       { wp1 = Wtp1 + (t + 64);  ws1 = 128; }
    else if (t < 128) { wp1 = Wtp2 + (t - 64);  ws1 = 64;  }
    else              { wp1 = Wtp3 + (t - 128); ws1 = 64;  }

    // ---- feat base indices ----
    const int f0 = (t < 128) ? t : (t - 128);            // c0: A->feat0[t]; B->feat0[u']
    int f1;
    if (t < 64)       f1 = t + 64;                        // c1 B: u'=t+64
    else if (t < 128) f1 = 128 + 3 * (t - 64);            // c1 C: u'=t-64
    else              f1 = 128 + 3 * (t - 128);           // c1 D: u'=t-128

    // acc meaning by wave:  t<64:   acc0=A(c0), acc1..3=B(c1)
    //                       64-128: acc0=A(c0), acc1..3=C(c1)
    //                       128+:   acc0=D(c1), acc1..3=B(c0)
    float acc0 = 0.f, acc1 = 0.f, acc2 = 0.f, acc3 = 0.f;
    const int beg = offsets[node], end = offsets[node + 1];

    for (int cb = beg; cb < end; cb += CHUNK) {
        const int ne = min(CHUNK, end - cb);
        if (t < ne) eids[t] = elist[cb + t];
        __syncthreads();
        if (t < ne) {
            srcs[t] = edge_src[eids[t]];
            ((float4*)ys)[t] = ((const float4*)edge_attr)[eids[t]];
        }
        // stage h2 rows (coalesced; zero-fill e >= ne)
        for (int x = t; x < CHUNK * 64; x += GT) {
            int e = x >> 6, k = x & 63;
            h2s[e * 68 + k] = (e < ne) ? h2buf[(size_t)eids[e] * 64 + k] : 0.f;
        }
        __syncthreads();

        // ---- projection: a0[e]=h2[e].col0, a1[e]=h2[e].col1 ----
        float a0[CHUNK], a1[CHUNK];
#pragma unroll
        for (int e = 0; e < CHUNK; ++e) { a0[e] = 0.f; a1[e] = 0.f; }
#pragma unroll
        for (int q = 0; q < 16; ++q) {
            const float w00 = wp0[(4 * q + 0) * ws0];
            const float w01 = wp0[(4 * q + 1) * ws0];
            const float w02 = wp0[(4 * q + 2) * ws0];
            const float w03 = wp0[(4 * q + 3) * ws0];
            const float w10 = wp1[(4 * q + 0) * ws1];
            const float w11 = wp1[(4 * q + 1) * ws1];
            const float w12 = wp1[(4 * q + 2) * ws1];
            const float w13 = wp1[(4 * q + 3) * ws1];
#pragma unroll
            for (int e = 0; e < CHUNK; ++e) {
                const float4 h = *(const float4*)(h2s + e * 68 + 4 * q);
                a0[e] += h.x * w00 + h.y * w01 + h.z * w02 + h.w * w03;
                a1[e] += h.x * w10 + h.y * w11 + h.z * w12 + h.w * w13;
            }
        }

        // ---- tensor product accumulate (wave-uniform branches) ----
        if (t < 64) {
#pragma unroll
            for (int e = 0; e < CHUNK; ++e) {
                if (e < ne) {
                    const float* fr = feat_tbl + (size_t)srcs[e] * FEAT_W;
                    acc0 += a0[e] * fr[f0] * ys[e][0];          // A
                    const float p = a1[e] * fr[f1];             // B
                    acc1 += p * ys[e][1];
                    acc2 += p * ys[e][2];
                    acc3 += p * ys[e][3];
                }
            }
        } else if (t < 128) {
#pragma unroll
            for (int e = 0; e < CHUNK; ++e) {
                if (e < ne) {
                    const float* fr = feat_tbl + (size_t)srcs[e] * FEAT_W;
                    acc0 += a0[e] * fr[f0] * ys[e][0];          // A
                    const float p = a1[e] * ys[e][0];           // C
                    acc1 += p * fr[f1];
                    acc2 += p * fr[f1 + 1];
                    acc3 += p * fr[f1 + 2];
                }
            }
        } else {
#pragma unroll
            for (int e = 0; e < CHUNK; ++e) {
                if (e < ne) {
                    const float* fr = feat_tbl + (size_t)srcs[e] * FEAT_W;
                    const float p = a0[e] * fr[f0];             // B (c0)
                    acc1 += p * ys[e][1];
                    acc2 += p * ys[e][2];
                    acc3 += p * ys[e][3];
                    const float d = fr[f1] * ys[e][1] + fr[f1 + 1] * ys[e][2]
                                  + fr[f1 + 2] * ys[e][3];      // D (c1)
                    acc0 += a1[e] * d;
                }
            }
        }
        __syncthreads();   // before next chunk overwrites LDS
    }

    // ---- write z (fold proj 1/8 and agg 1/sqrt(16)) ----
    const float sZ = 0.125f * 0.25f;
    if (t < 64) {
        z[t] = acc0 * sZ;                                  // mid0a col t
        const int u = t + 64;                              // c1 B -> z1 row u
        z[192 + 0 * 192 + u] = acc1 * sZ;
        z[192 + 1 * 192 + u] = acc2 * sZ;
        z[192 + 2 * 192 + u] = acc3 * sZ;
    } else if (t < 128) {
        z[t] = acc0 * sZ;                                  // mid0a col t
        const int u = 128 + (t - 64);                      // c1 C -> z1 row 128+u'
        z[192 + 0 * 192 + u] = acc1 * sZ;
        z[192 + 1 * 192 + u] = acc2 * sZ;
        z[192 + 2 * 192 + u] = acc3 * sZ;
    } else {
        const int u = t - 128;                             // c0 B -> z1 row u
        z[192 + 0 * 192 + u] = acc1 * sZ;
        z[192 + 1 * 192 + u] = acc2 * sZ;
        z[192 + 2 * 192 + u] = acc3 * sZ;
        z[128 + u] = acc0 * sZ * 0.5773502691896258f;      // c1 D -> mid0b, 1/sqrt(3)
    }
    __syncthreads();

    // ---- output GEMM + rotation combine (2 outputs per thread) ----
    const float sA = 0.07216878364870323f;   // 1/sqrt(192)
    const float cR = 0.92387953251128674f;   // cos(pi/8)
    const float sR = 0.38268343236508978f;   // sin(pi/8)

#pragma unroll
    for (int g = 0; g < 2; ++g) {
        const int jj = t + g * GT;           // 0..383; skip >=320
        if (jj < 128) {
            float conv = 0.f;
            const float4* z4 = (const float4*)z;
#pragma unroll 8
            for (int q = 0; q < 48; ++q) {
                const float4 zz = z4[q];
                conv += zz.x * Wo0[(4 * q + 0) * 128 + jj];
                conv += zz.y * Wo0[(4 * q + 1) * 128 + jj];
                conv += zz.z * Wo0[(4 * q + 2) * 128 + jj];
                conv += zz.w * Wo0[(4 * q + 3) * 128 + jj];
            }
            const float sv = self_tbl[(size_t)node * FEAT_W + jj];
            out[(size_t)node * FEAT_W + jj] = cR * sv + sR * conv * sA;
        } else if (jj < 320) {
            const int idx = jj - 128;
            const int i = idx >> 6, u = idx & 63;
            float conv = 0.f;
            const float4* z4 = (const float4*)(z + 192 + i * 192);
#pragma unroll 8
            for (int q = 0; q < 48; ++q) {
                const float4 zz = z4[q];
                conv += zz.x * Wo1[(4 * q + 0) * 64 + u];
                conv += zz.y * Wo1[(4 * q + 1) * 64 + u];
                conv += zz.z * Wo1[(4 * q + 2) * 64 + u];
                conv += zz.w * Wo1[(4 * q + 3) * 64 + u];
            }
            const int col = 128 + u * 3 + i;
            const float sv = self_tbl[(size_t)node * FEAT_W + col];
            out[(size_t)node * FEAT_W + col] = cR * sv + sR * conv * sA;
        }
    }
}

extern "C" void kernel_launch(void* const* d_in, const int* in_sizes, int n_in,
                              void* d_out, int out_size, void* d_ws, size_t ws_size,
                              hipStream_t stream) {
    const float* node_input = (const float*)d_in[0];
    const float* edge_attr  = (const float*)d_in[1];
    const float* esa        = (const float*)d_in[2];
    const float* Wa0  = (const float*)d_in[3];
    const float* Wa1  = (const float*)d_in[4];
    const float* Wb0  = (const float*)d_in[5];
    const float* Wb1  = (const float*)d_in[6];
    const float* M1   = (const float*)d_in[7];
    const float* M2   = (const float*)d_in[8];
    const float* Wtp0 = (const float*)d_in[9];
    const float* Wtp1 = (const float*)d_in[10];
    const float* Wtp2 = (const float*)d_in[11];
    const float* Wtp3 = (const float*)d_in[12];
    const float* Wo0  = (const float*)d_in[13];
    const float* Wo1  = (const float*)d_in[14];
    const int* edge_src = (const int*)d_in[15];
    const int* edge_dst = (const int*)d_in[16];
    float* out = (float*)d_out;

    // ws usage: 16.64M floats + 0.34M ints ~= 68 MB (proven in R2-R9)
    float* feat_tbl = (float*)d_ws;                               // 10000*320
    float* self_tbl = feat_tbl + (size_t)N_NODES * FEAT_W;        // 10000*320
    float* h2buf    = self_tbl + (size_t)N_NODES * FEAT_W;        // 160000*64
    int*   counts   = (int*)(h2buf + (size_t)N_EDGES * 64);       // 10000
    int*   offsets  = counts + N_NODES;                           // 10001
    int*   cursor   = offsets + N_NODES + 1;                      // 10000
    int*   elist    = cursor + N_NODES;                           // 160000

    hipMemsetAsync(counts, 0, sizeof(int) * N_NODES, stream);

    node_transform<<<N_NODES / 8, 256, 0, stream>>>(node_input, Wa0, Wa1, Wb0, Wb1,
                                                    feat_tbl, self_tbl);
    mlp_kernel<<<N_EDGES / 4, 256, 0, stream>>>(esa, M1, M2, h2buf);
    count_kernel<<<N_EDGES / 256, 256, 0, stream>>>(edge_dst, counts);
    scan_kernel<<<1, 1024, 0, stream>>>(counts, offsets, cursor);
    fill_kernel<<<N_EDGES / 256, 256, 0, stream>>>(edge_dst, cursor, elist);
    gather_kernel<<<N_NODES, GT, 0, stream>>>(offsets, elist, edge_src,
                                              edge_attr, h2buf, feat_tbl, self_tbl,
                                              Wtp0, Wtp1, Wtp2, Wtp3, Wo0, Wo1, out);
}

// Round 11
// 515.036 us; speedup vs baseline: 2.1837x; 2.1837x over previous
//
#include <hip/hip_runtime.h>
#include <hip/hip_bf16.h>
#include <hip/hip_fp16.h>

#define N_NODES 10000
#define N_EDGES 160000
#define FEAT_W 320
#define CHUNK 16
#define WPE 64    // edges per wproj block

__device__ __forceinline__ float gelu_tanh(float x) {
    float x3 = x * x * x;
    float t = tanhf(0.7978845608028654f * (x + 0.044715f * x3));
    return 0.5f * x * (1.0f + t);
}

// ---------------- Kernel 1: node transforms, 8 nodes/block ------------------
// feat_tbl / self_tbl rows: [0..128) = mul0 part, [128..320) = mul1 part as u*3+i
__global__ __launch_bounds__(256) void node_transform(
    const float* __restrict__ node_input,
    const float* __restrict__ Wa0, const float* __restrict__ Wa1,
    const float* __restrict__ Wb0, const float* __restrict__ Wb1,
    float* __restrict__ feat_tbl, float* __restrict__ self_tbl)
{
    __shared__ float x[8][FEAT_W];         // 10.24 KB
    const int node0 = blockIdx.x * 8;
    const int t = threadIdx.x;
    for (int q = t; q < 8 * FEAT_W / 4; q += 256)
        ((float4*)x)[q] = ((const float4*)(node_input + (size_t)node0 * FEAT_W))[q];
    __syncthreads();

    for (int g = 0; g < 3; ++g) {
        const int oidx = t + g * 256;
        if (oidx >= 640) break;
        const bool is_self = (oidx >= 320);
        const int idx = is_self ? oidx - 320 : oidx;
        float acc[8] = {0, 0, 0, 0, 0, 0, 0, 0};
        if (idx < 128) {
            const float* W = is_self ? Wb0 : Wa0;
            for (int v = 0; v < 128; ++v) {
                const float wv = W[v * 128 + idx];
#pragma unroll
                for (int n = 0; n < 8; ++n) acc[n] += x[n][v] * wv;
            }
#pragma unroll
            for (int n = 0; n < 8; ++n) acc[n] *= 0.08838834764831845f;  // 1/sqrt(128)
        } else {
            const int r = idx - 128, u = r / 3, i = r - 3 * u;
            const float* W = is_self ? Wb1 : Wa1;
            for (int v = 0; v < 64; ++v) {
                const float wv = W[v * 64 + u];
#pragma unroll
                for (int n = 0; n < 8; ++n) acc[n] += x[n][128 + v * 3 + i] * wv;
            }
#pragma unroll
            for (int n = 0; n < 8; ++n) acc[n] *= 0.125f;                // 1/sqrt(64)
        }
        float* outp = is_self ? self_tbl : feat_tbl;
#pragma unroll
        for (int n = 0; n < 8; ++n)
            outp[(size_t)(node0 + n) * FEAT_W + idx] = acc[n];
    }
}

// ---------------- Kernel 2: per-edge MLP -> h2 ------------------------------
__global__ __launch_bounds__(256) void mlp_kernel(
    const float* __restrict__ esa,   // (E,8)
    const float* __restrict__ M1,    // (8,64)
    const float* __restrict__ M2,    // (64,64)
    float* __restrict__ h2buf)       // (E,64)
{
    __shared__ float sh[4][64];
    const int wave = threadIdx.x >> 6;
    const int lane = threadIdx.x & 63;
    const int e = blockIdx.x * 4 + wave;   // N_EDGES % 4 == 0

    const float* er = esa + (size_t)e * 8;
    float h = 0.f;
#pragma unroll
    for (int k = 0; k < 8; ++k) h += er[k] * M1[k * 64 + lane];
    h = gelu_tanh(h * 0.35355339059327373f);   // 1/sqrt(8)
    sh[wave][lane] = h;
    __syncthreads();

    float h2 = 0.f;
    for (int v = 0; v < 64; ++v) h2 += sh[wave][v] * M2[v * 64 + lane];
    h2 = gelu_tanh(h2 * 0.125f);               // 1/sqrt(64)
    h2buf[(size_t)e * 64 + lane] = h2;
}

// ---------------- CSR build -------------------------------------------------
__global__ void count_kernel(const int* __restrict__ edge_dst, int* __restrict__ counts) {
    int e = blockIdx.x * 256 + threadIdx.x;
    if (e < N_EDGES) atomicAdd(&counts[edge_dst[e]], 1);
}

__global__ __launch_bounds__(1024) void scan_kernel(
    const int* __restrict__ counts, int* __restrict__ offsets, int* __restrict__ cursor)
{
    __shared__ int buf[1024];
    int base = 0;
    for (int c = 0; c < 10; ++c) {            // 10*1024 >= 10000
        int i = c * 1024 + threadIdx.x;
        int v = (i < N_NODES) ? counts[i] : 0;
        buf[threadIdx.x] = v;
        __syncthreads();
        for (int off = 1; off < 1024; off <<= 1) {
            int t = (threadIdx.x >= off) ? buf[threadIdx.x - off] : 0;
            __syncthreads();
            buf[threadIdx.x] += t;
            __syncthreads();
        }
        int excl = buf[threadIdx.x] - v;
        if (i < N_NODES) { offsets[i] = base + excl; cursor[i] = base + excl; }
        int tot = buf[1023];
        __syncthreads();
        base += tot;
    }
    if (threadIdx.x == 0) offsets[N_NODES] = base;
}

__global__ void fill_kernel(const int* __restrict__ edge_dst,
                            int* __restrict__ cursor, int* __restrict__ elist) {
    int e = blockIdx.x * 256 + threadIdx.x;
    if (e < N_EDGES) {
        int pos = atomicAdd(&cursor[edge_dst[e]], 1);
        elist[pos] = e;
    }
}

// ---------------- Kernel 3: W-projection GEMM, CSR-ordered f16 output -------
// grid (2500, 3): block = 64 CSR edges x 128 cols (col group g: 0->Wtp0,
// 1->Wtp1, 2->[Wtp2|Wtp3]). h2 k-major in LDS + W tile in LDS; thread tile
// 8 edges x 4 cols = 32 accs. Output folds the 1/sqrt(64) proj scale.
__global__ __launch_bounds__(256) void wproj_kernel(
    const int* __restrict__ elist,
    const float* __restrict__ h2buf,       // (E,64)
    const float* __restrict__ Wtp0,        // (64,128)
    const float* __restrict__ Wtp1,        // (64,128)
    const float* __restrict__ Wtp2,        // (64,64)
    const float* __restrict__ Wtp3,        // (64,64)
    __half* __restrict__ wbuf)             // (E,384) f16, CSR order
{
    __shared__ __align__(16) float h2T[64 * 68];   // [k][e], stride 68: 17.4 KB
    __shared__ __align__(16) float Wt[64 * 128];   // [k][c]: 32 KB
    const int t = threadIdx.x;
    const int pbase = blockIdx.x * WPE;            // 2500*64 == N_EDGES
    const int g = blockIdx.y;

    // stage h2T (global reads coalesced along k; one edge row per wave pass)
#pragma unroll
    for (int i = 0; i < WPE * 64 / 256; ++i) {     // 16 iters
        const int x = i * 256 + t;
        const int e = x >> 6, k = x & 63;
        const int eid = elist[pbase + e];
        h2T[k * 68 + e] = h2buf[(size_t)eid * 64 + k];
    }
    // stage Wt (float4 rows)
#pragma unroll
    for (int i = 0; i < 8; ++i) {                  // 8*256 = 2048 float4s
        const int x = i * 256 + t;
        const int k = x >> 5, c4 = x & 31;
        float4 w;
        if (g == 0)      w = ((const float4*)(Wtp0 + k * 128))[c4];
        else if (g == 1) w = ((const float4*)(Wtp1 + k * 128))[c4];
        else             w = (c4 < 16) ? ((const float4*)(Wtp2 + k * 64))[c4]
                                       : ((const float4*)(Wtp3 + k * 64))[c4 - 16];
        ((float4*)(Wt + k * 128))[c4] = w;
    }
    __syncthreads();

    const int e0 = (t >> 5) * 8;     // 8 edge-groups
    const int c0 = (t & 31) * 4;     // 32 col-groups
    float acc[8][4] = {};
#pragma unroll 8
    for (int k = 0; k < 64; ++k) {
        const float4 ha = *(const float4*)(h2T + k * 68 + e0);
        const float4 hb = *(const float4*)(h2T + k * 68 + e0 + 4);
        const float4 wv = *(const float4*)(Wt + k * 128 + c0);
        const float he[8] = {ha.x, ha.y, ha.z, ha.w, hb.x, hb.y, hb.z, hb.w};
#pragma unroll
        for (int e = 0; e < 8; ++e)
#pragma unroll
            for (int j = 0; j < 4; ++j)
                acc[e][j] += he[e] * (&wv.x)[j];
    }

    const float s8 = 0.125f;   // 1/sqrt(64)
#pragma unroll
    for (int e = 0; e < 8; ++e) {
        __half2 p0 = __floats2half2_rn(acc[e][0] * s8, acc[e][1] * s8);
        __half2 p1 = __floats2half2_rn(acc[e][2] * s8, acc[e][3] * s8);
        __half2* dst = (__half2*)(wbuf + (size_t)(pbase + e0 + e) * 384 + g * 128 + c0);
        dst[0] = p0;
        dst[1] = p1;
    }
}

// ---------------- Kernel 4: slim gather: TP + out-GEMM ----------------------
// 384 threads/block, one block per node. Thread t consumes wbuf column t
// (coalesced f16 global reads). Same validated mapping as R9:
//   t<128: A mid0a | t<256: B mid1a (3 accs) | t<320: C mid1b (3) | else: D mid0b
// z layout: [0,192)=z0; [192 + i*192 + v)=z1[v][i] planes.
__global__ __launch_bounds__(384) void gather_kernel(
    const int* __restrict__ offsets, const int* __restrict__ elist,
    const int* __restrict__ edge_src,
    const float* __restrict__ edge_attr,   // (E,4)
    const __half* __restrict__ wbuf,       // (E,384) CSR order, pre-scaled 1/8
    const float* __restrict__ feat_tbl,    // (N,320)
    const float* __restrict__ self_tbl,    // (N,320)
    const float* __restrict__ Wo0,         // (192,128)
    const float* __restrict__ Wo1,         // (192,64)
    float* __restrict__ out)               // (N,320)
{
    __shared__ float ys[CHUNK][4];
    __shared__ int   eids[CHUNK];
    __shared__ int   srcs[CHUNK];
    __shared__ float z[768];

    const int node = blockIdx.x;
    const int t = threadIdx.x;             // 0..383

    int f0;
    if (t < 128)      f0 = t;
    else if (t < 256) f0 = t - 128;
    else if (t < 320) f0 = 128 + 3 * (t - 256);
    else              f0 = 128 + 3 * (t - 320);

    float acc = 0.f, acc3a = 0.f, acc3b = 0.f, acc3c = 0.f;
    const int beg = offsets[node], end = offsets[node + 1];

    for (int cb = beg; cb < end; cb += CHUNK) {
        const int ne = min(CHUNK, end - cb);
        if (t < ne) eids[t] = elist[cb + t];
        __syncthreads();
        if (t < ne) {
            srcs[t] = edge_src[eids[t]];
            ((float4*)ys)[t] = ((const float4*)edge_attr)[eids[t]];
        }
        __syncthreads();

        if (t < 128) {                       // A: mid0a
#pragma unroll
            for (int e = 0; e < CHUNK; ++e) {
                if (e < ne) {
                    const float w = __half2float(wbuf[(size_t)(cb + e) * 384 + t]);
                    const float* fr = feat_tbl + (size_t)srcs[e] * FEAT_W;
                    acc += w * fr[f0] * ys[e][0];
                }
            }
        } else if (t < 256) {                // B: mid1a
#pragma unroll
            for (int e = 0; e < CHUNK; ++e) {
                if (e < ne) {
                    const float w = __half2float(wbuf[(size_t)(cb + e) * 384 + t]);
                    const float* fr = feat_tbl + (size_t)srcs[e] * FEAT_W;
                    const float p = w * fr[f0];
                    acc3a += p * ys[e][1];
                    acc3b += p * ys[e][2];
                    acc3c += p * ys[e][3];
                }
            }
        } else if (t < 320) {                // C: mid1b
#pragma unroll
            for (int e = 0; e < CHUNK; ++e) {
                if (e < ne) {
                    const float w = __half2float(wbuf[(size_t)(cb + e) * 384 + t]);
                    const float* fr = feat_tbl + (size_t)srcs[e] * FEAT_W;
                    const float p = w * ys[e][0];
                    acc3a += p * fr[f0];
                    acc3b += p * fr[f0 + 1];
                    acc3c += p * fr[f0 + 2];
                }
            }
        } else {                             // D: mid0b
#pragma unroll
            for (int e = 0; e < CHUNK; ++e) {
                if (e < ne) {
                    const float w = __half2float(wbuf[(size_t)(cb + e) * 384 + t]);
                    const float* fr = feat_tbl + (size_t)srcs[e] * FEAT_W;
                    const float d = fr[f0] * ys[e][1] + fr[f0 + 1] * ys[e][2]
                                  + fr[f0 + 2] * ys[e][3];
                    acc += w * d;
                }
            }
        }
        __syncthreads();   // before next chunk overwrites LDS
    }

    // ---- write z (proj 1/8 already folded in wbuf; agg 1/sqrt(16) here) ----
    const float sZ = 0.25f;
    if (t < 128) {
        z[t] = acc * sZ;
    } else if (t < 256) {
        const int u = t - 128;
        z[192 + 0 * 192 + u] = acc3a * sZ;
        z[192 + 1 * 192 + u] = acc3b * sZ;
        z[192 + 2 * 192 + u] = acc3c * sZ;
    } else if (t < 320) {
        const int u = t - 256;
        z[192 + 0 * 192 + 128 + u] = acc3a * sZ;
        z[192 + 1 * 192 + 128 + u] = acc3b * sZ;
        z[192 + 2 * 192 + 128 + u] = acc3c * sZ;
    } else {
        z[128 + (t - 320)] = acc * sZ * 0.5773502691896258f;  // mid0b, 1/sqrt(3)
    }
    __syncthreads();

    // ---- output GEMM + rotation combine ----
    const float sA = 0.07216878364870323f;   // 1/sqrt(192)
    const float cR = 0.92387953251128674f;   // cos(pi/8)
    const float sR = 0.38268343236508978f;   // sin(pi/8)

    if (t < 128) {
        float conv = 0.f;
        const float4* z4 = (const float4*)z;
#pragma unroll 8
        for (int q = 0; q < 48; ++q) {
            const float4 zz = z4[q];
            conv += zz.x * Wo0[(4 * q + 0) * 128 + t];
            conv += zz.y * Wo0[(4 * q + 1) * 128 + t];
            conv += zz.z * Wo0[(4 * q + 2) * 128 + t];
            conv += zz.w * Wo0[(4 * q + 3) * 128 + t];
        }
        const float sv = self_tbl[(size_t)node * FEAT_W + t];
        out[(size_t)node * FEAT_W + t] = cR * sv + sR * conv * sA;
    } else if (t < 320) {
        const int idx = t - 128;
        const int i = idx >> 6, u = idx & 63;
        float conv = 0.f;
        const float4* z4 = (const float4*)(z + 192 + i * 192);
#pragma unroll 8
        for (int q = 0; q < 48; ++q) {
            const float4 zz = z4[q];
            conv += zz.x * Wo1[(4 * q + 0) * 64 + u];
            conv += zz.y * Wo1[(4 * q + 1) * 64 + u];
            conv += zz.z * Wo1[(4 * q + 2) * 64 + u];
            conv += zz.w * Wo1[(4 * q + 3) * 64 + u];
        }
        const int col = 128 + u * 3 + i;
        const float sv = self_tbl[(size_t)node * FEAT_W + col];
        out[(size_t)node * FEAT_W + col] = cR * sv + sR * conv * sA;
    }
}

extern "C" void kernel_launch(void* const* d_in, const int* in_sizes, int n_in,
                              void* d_out, int out_size, void* d_ws, size_t ws_size,
                              hipStream_t stream) {
    const float* node_input = (const float*)d_in[0];
    const float* edge_attr  = (const float*)d_in[1];
    const float* esa        = (const float*)d_in[2];
    const float* Wa0  = (const float*)d_in[3];
    const float* Wa1  = (const float*)d_in[4];
    const float* Wb0  = (const float*)d_in[5];
    const float* Wb1  = (const float*)d_in[6];
    const float* M1   = (const float*)d_in[7];
    const float* M2   = (const float*)d_in[8];
    const float* Wtp0 = (const float*)d_in[9];
    const float* Wtp1 = (const float*)d_in[10];
    const float* Wtp2 = (const float*)d_in[11];
    const float* Wtp3 = (const float*)d_in[12];
    const float* Wo0  = (const float*)d_in[13];
    const float* Wo1  = (const float*)d_in[14];
    const int* edge_src = (const int*)d_in[15];
    const int* edge_dst = (const int*)d_in[16];
    float* out = (float*)d_out;

    // ws usage: 68 MB (R2-R10 proven) + 123 MB f16 wbuf = ~191 MB
    float*  feat_tbl = (float*)d_ws;                              // 10000*320
    float*  self_tbl = feat_tbl + (size_t)N_NODES * FEAT_W;       // 10000*320
    float*  h2buf    = self_tbl + (size_t)N_NODES * FEAT_W;       // 160000*64
    int*    counts   = (int*)(h2buf + (size_t)N_EDGES * 64);      // 10000
    int*    offsets  = counts + N_NODES;                          // 10001
    int*    cursor   = offsets + N_NODES + 1;                     // 10000
    int*    elist    = cursor + N_NODES;                          // 160000
    __half* wbuf     = (__half*)(elist + N_EDGES);                // 160000*384 f16

    hipMemsetAsync(counts, 0, sizeof(int) * N_NODES, stream);

    node_transform<<<N_NODES / 8, 256, 0, stream>>>(node_input, Wa0, Wa1, Wb0, Wb1,
                                                    feat_tbl, self_tbl);
    mlp_kernel<<<N_EDGES / 4, 256, 0, stream>>>(esa, M1, M2, h2buf);
    count_kernel<<<N_EDGES / 256, 256, 0, stream>>>(edge_dst, counts);
    scan_kernel<<<1, 1024, 0, stream>>>(counts, offsets, cursor);
    fill_kernel<<<N_EDGES / 256, 256, 0, stream>>>(edge_dst, cursor, elist);
    wproj_kernel<<<dim3(N_EDGES / WPE, 3), 256, 0, stream>>>(
        elist, h2buf, Wtp0, Wtp1, Wtp2, Wtp3, wbuf);
    gather_kernel<<<N_NODES, 384, 0, stream>>>(offsets, elist, edge_src,
                                               edge_attr, wbuf, feat_tbl, self_tbl,
                                               Wo0, Wo1, out);
}

// Round 12
// 461.578 us; speedup vs baseline: 2.4366x; 1.1158x over previous
//
#include <hip/hip_runtime.h>
#include <hip/hip_bf16.h>
#include <hip/hip_fp16.h>

#define N_NODES 10000
#define N_EDGES 160000
#define FEAT_W 320
#define CHUNK 16
#define WPE 64    // edges per wproj block

typedef _Float16 half8 __attribute__((ext_vector_type(8)));
typedef float f32x4 __attribute__((ext_vector_type(4)));

__device__ __forceinline__ float gelu_tanh(float x) {
    float x3 = x * x * x;
    float t = tanhf(0.7978845608028654f * (x + 0.044715f * x3));
    return 0.5f * x * (1.0f + t);
}

// ---------------- Kernel 1: node transforms, 8 nodes/block ------------------
// feat_tbl / self_tbl rows: [0..128) = mul0 part, [128..320) = mul1 part as u*3+i
__global__ __launch_bounds__(256) void node_transform(
    const float* __restrict__ node_input,
    const float* __restrict__ Wa0, const float* __restrict__ Wa1,
    const float* __restrict__ Wb0, const float* __restrict__ Wb1,
    float* __restrict__ feat_tbl, float* __restrict__ self_tbl)
{
    __shared__ float x[8][FEAT_W];         // 10.24 KB
    const int node0 = blockIdx.x * 8;
    const int t = threadIdx.x;
    for (int q = t; q < 8 * FEAT_W / 4; q += 256)
        ((float4*)x)[q] = ((const float4*)(node_input + (size_t)node0 * FEAT_W))[q];
    __syncthreads();

    for (int g = 0; g < 3; ++g) {
        const int oidx = t + g * 256;
        if (oidx >= 640) break;
        const bool is_self = (oidx >= 320);
        const int idx = is_self ? oidx - 320 : oidx;
        float acc[8] = {0, 0, 0, 0, 0, 0, 0, 0};
        if (idx < 128) {
            const float* W = is_self ? Wb0 : Wa0;
            for (int v = 0; v < 128; ++v) {
                const float wv = W[v * 128 + idx];
#pragma unroll
                for (int n = 0; n < 8; ++n) acc[n] += x[n][v] * wv;
            }
#pragma unroll
            for (int n = 0; n < 8; ++n) acc[n] *= 0.08838834764831845f;  // 1/sqrt(128)
        } else {
            const int r = idx - 128, u = r / 3, i = r - 3 * u;
            const float* W = is_self ? Wb1 : Wa1;
            for (int v = 0; v < 64; ++v) {
                const float wv = W[v * 64 + u];
#pragma unroll
                for (int n = 0; n < 8; ++n) acc[n] += x[n][128 + v * 3 + i] * wv;
            }
#pragma unroll
            for (int n = 0; n < 8; ++n) acc[n] *= 0.125f;                // 1/sqrt(64)
        }
        float* outp = is_self ? self_tbl : feat_tbl;
#pragma unroll
        for (int n = 0; n < 8; ++n)
            outp[(size_t)(node0 + n) * FEAT_W + idx] = acc[n];
    }
}

// ---------------- Kernel 2: per-edge MLP -> h2 (+ degree count fused) -------
__global__ __launch_bounds__(256) void mlp_kernel(
    const float* __restrict__ esa,   // (E,8)
    const float* __restrict__ M1,    // (8,64)
    const float* __restrict__ M2,    // (64,64)
    const int* __restrict__ edge_dst,
    float* __restrict__ h2buf,       // (E,64)
    int* __restrict__ counts)
{
    __shared__ float sh[4][64];
    const int wave = threadIdx.x >> 6;
    const int lane = threadIdx.x & 63;
    const int e = blockIdx.x * 4 + wave;   // N_EDGES % 4 == 0

    if (lane == 0) atomicAdd(&counts[edge_dst[e]], 1);

    const float* er = esa + (size_t)e * 8;
    float h = 0.f;
#pragma unroll
    for (int k = 0; k < 8; ++k) h += er[k] * M1[k * 64 + lane];
    h = gelu_tanh(h * 0.35355339059327373f);   // 1/sqrt(8)
    sh[wave][lane] = h;
    __syncthreads();

    float h2 = 0.f;
    for (int v = 0; v < 64; ++v) h2 += sh[wave][v] * M2[v * 64 + lane];
    h2 = gelu_tanh(h2 * 0.125f);               // 1/sqrt(64)
    h2buf[(size_t)e * 64 + lane] = h2;
}

// ---------------- CSR build -------------------------------------------------
__global__ __launch_bounds__(1024) void scan_kernel(
    const int* __restrict__ counts, int* __restrict__ offsets, int* __restrict__ cursor)
{
    __shared__ int wsum[16];
    const int wid = threadIdx.x >> 6, lane = threadIdx.x & 63;
    int base = 0;
    for (int c = 0; c < 10; ++c) {            // 10*1024 >= 10000
        const int i = c * 1024 + threadIdx.x;
        const int v = (i < N_NODES) ? counts[i] : 0;
        int x = v;
#pragma unroll
        for (int off = 1; off < 64; off <<= 1) {
            int y = __shfl_up(x, off, 64);
            if (lane >= off) x += y;
        }
        if (lane == 63) wsum[wid] = x;
        __syncthreads();
        if (threadIdx.x < 16) {
            int s = wsum[threadIdx.x];
#pragma unroll
            for (int off = 1; off < 16; off <<= 1) {
                int y = __shfl_up(s, off, 64);
                if ((int)threadIdx.x >= off) s += y;
            }
            wsum[threadIdx.x] = s;
        }
        __syncthreads();
        const int waveoff = (wid == 0) ? 0 : wsum[wid - 1];
        const int excl = base + waveoff + x - v;
        if (i < N_NODES) { offsets[i] = excl; cursor[i] = excl; }
        const int tot = wsum[15];
        __syncthreads();
        base += tot;
    }
    if (threadIdx.x == 0) offsets[N_NODES] = base;
}

__global__ void fill_kernel(const int* __restrict__ edge_dst,
                            int* __restrict__ cursor, int* __restrict__ elist) {
    int e = blockIdx.x * 256 + threadIdx.x;
    if (e < N_EDGES) {
        int pos = atomicAdd(&cursor[edge_dst[e]], 1);
        elist[pos] = e;
    }
}

// ---------------- Kernel 3: W-projection via MFMA f16 -----------------------
// grid 2500 blocks x 4 waves. Block = 64 CSR edges x 384 cols; wave owns 96
// cols (6 16-col tiles, B frags in regs), loops 4 edge-groups of 16.
// Layouts (HW-verified, learn_hip m89/m120): A[m=lane&15][k=quad*8+j],
// B[k=quad*8+j][n=lane&15], D col=lane&15 row=quad*4+reg.
__global__ __launch_bounds__(256) void wproj_kernel(
    const int* __restrict__ elist,
    const float* __restrict__ h2buf,       // (E,64)
    const float* __restrict__ Wtp0,        // (64,128)
    const float* __restrict__ Wtp1,        // (64,128)
    const float* __restrict__ Wtp2,        // (64,64)
    const float* __restrict__ Wtp3,        // (64,64)
    __half* __restrict__ wbuf)             // (E,384) f16, CSR order, pre-scaled 1/8
{
    const int wave = threadIdx.x >> 6;
    const int lane = threadIdx.x & 63;
    const int quad = lane >> 4;
    const int n16 = lane & 15;
    const int pbase = blockIdx.x * WPE;    // 2500*64 == N_EDGES
    const int colbase = wave * 96;

    // ---- B fragments for this wave's 6 col-tiles (k = s*32 + quad*8 + j) ----
    half8 bf[6][2];
#pragma unroll
    for (int c = 0; c < 6; ++c) {
        const int col = colbase + c * 16 + n16;
        const float* src; int stride;
        if (col < 128)      { src = Wtp0 + col;         stride = 128; }
        else if (col < 256) { src = Wtp1 + (col - 128); stride = 128; }
        else if (col < 320) { src = Wtp2 + (col - 256); stride = 64;  }
        else                { src = Wtp3 + (col - 320); stride = 64;  }
#pragma unroll
        for (int s = 0; s < 2; ++s)
#pragma unroll
            for (int j = 0; j < 8; ++j)
                bf[c][s][j] = (_Float16)src[(s * 32 + quad * 8 + j) * stride];
    }

    // ---- 4 edge groups of 16 ----
    for (int g = 0; g < 4; ++g) {
        const int eid = elist[pbase + g * 16 + n16];   // A row m = n16
        const float* hrow = h2buf + (size_t)eid * 64;
        half8 af[2];
#pragma unroll
        for (int s = 0; s < 2; ++s) {
            const float4 p0 = *(const float4*)(hrow + s * 32 + quad * 8);
            const float4 p1 = *(const float4*)(hrow + s * 32 + quad * 8 + 4);
            af[s][0] = (_Float16)p0.x; af[s][1] = (_Float16)p0.y;
            af[s][2] = (_Float16)p0.z; af[s][3] = (_Float16)p0.w;
            af[s][4] = (_Float16)p1.x; af[s][5] = (_Float16)p1.y;
            af[s][6] = (_Float16)p1.z; af[s][7] = (_Float16)p1.w;
        }
#pragma unroll
        for (int c = 0; c < 6; ++c) {
            f32x4 acc = {0.f, 0.f, 0.f, 0.f};
            acc = __builtin_amdgcn_mfma_f32_16x16x32_f16(af[0], bf[c][0], acc, 0, 0, 0);
            acc = __builtin_amdgcn_mfma_f32_16x16x32_f16(af[1], bf[c][1], acc, 0, 0, 0);
#pragma unroll
            for (int r = 0; r < 4; ++r) {
                const int edge = g * 16 + quad * 4 + r;          // D row
                wbuf[(size_t)(pbase + edge) * 384 + colbase + c * 16 + n16] =
                    (__half)(acc[r] * 0.125f);                   // 1/sqrt(64)
            }
        }
    }
}

// ---------------- Kernel 4: slim gather: TP + out-GEMM ----------------------
// 384 threads/block, one block per node. w-tile for the chunk staged into LDS
// via coalesced float4 (2 VMEM/thread), consumed as ds_read_u16.
// Mapping (R9-validated): t<128: A mid0a | t<256: B mid1a | t<320: C mid1b | else D mid0b.
// z layout: [0,192)=z0; [192 + i*192 + v)=z1[v][i] planes.
__global__ __launch_bounds__(384) void gather_kernel(
    const int* __restrict__ offsets, const int* __restrict__ elist,
    const int* __restrict__ edge_src,
    const float* __restrict__ edge_attr,   // (E,4)
    const __half* __restrict__ wbuf,       // (E,384) CSR order, pre-scaled 1/8
    const float* __restrict__ feat_tbl,    // (N,320)
    const float* __restrict__ self_tbl,    // (N,320)
    const float* __restrict__ Wo0,         // (192,128)
    const float* __restrict__ Wo1,         // (192,64)
    float* __restrict__ out)               // (N,320)
{
    __shared__ __align__(16) __half wsh[CHUNK * 384];  // 12 KB
    __shared__ float ys[CHUNK][4];
    __shared__ int   eids[CHUNK];
    __shared__ int   srcs[CHUNK];
    __shared__ float z[768];

    const int node = blockIdx.x;
    const int t = threadIdx.x;             // 0..383

    int f0;
    if (t < 128)      f0 = t;
    else if (t < 256) f0 = t - 128;
    else if (t < 320) f0 = 128 + 3 * (t - 256);
    else              f0 = 128 + 3 * (t - 320);

    float acc = 0.f, acc3a = 0.f, acc3b = 0.f, acc3c = 0.f;
    const int beg = offsets[node], end = offsets[node + 1];

    for (int cb = beg; cb < end; cb += CHUNK) {
        const int ne = min(CHUNK, end - cb);
        if (t < ne) eids[t] = elist[cb + t];
        __syncthreads();
        if (t < ne) {
            srcs[t] = edge_src[eids[t]];
            ((float4*)ys)[t] = ((const float4*)edge_attr)[eids[t]];
        }
        // stage w tile (ne*384 f16 = ne*48 float4), coalesced
        for (int q = t; q < ne * 48; q += 384)
            ((float4*)wsh)[q] = ((const float4*)(wbuf + (size_t)cb * 384))[q];
        __syncthreads();

        if (t < 128) {                       // A: mid0a
#pragma unroll
            for (int e = 0; e < CHUNK; ++e) {
                if (e < ne) {
                    const float w = __half2float(wsh[e * 384 + t]);
                    const float* fr = feat_tbl + (size_t)srcs[e] * FEAT_W;
                    acc += w * fr[f0] * ys[e][0];
                }
            }
        } else if (t < 256) {                // B: mid1a
#pragma unroll
            for (int e = 0; e < CHUNK; ++e) {
                if (e < ne) {
                    const float w = __half2float(wsh[e * 384 + t]);
                    const float* fr = feat_tbl + (size_t)srcs[e] * FEAT_W;
                    const float p = w * fr[f0];
                    acc3a += p * ys[e][1];
                    acc3b += p * ys[e][2];
                    acc3c += p * ys[e][3];
                }
            }
        } else if (t < 320) {                // C: mid1b
#pragma unroll
            for (int e = 0; e < CHUNK; ++e) {
                if (e < ne) {
                    const float w = __half2float(wsh[e * 384 + t]);
                    const float* fr = feat_tbl + (size_t)srcs[e] * FEAT_W;
                    const float p = w * ys[e][0];
                    acc3a += p * fr[f0];
                    acc3b += p * fr[f0 + 1];
                    acc3c += p * fr[f0 + 2];
                }
            }
        } else {                             // D: mid0b
#pragma unroll
            for (int e = 0; e < CHUNK; ++e) {
                if (e < ne) {
                    const float w = __half2float(wsh[e * 384 + t]);
                    const float* fr = feat_tbl + (size_t)srcs[e] * FEAT_W;
                    const float d = fr[f0] * ys[e][1] + fr[f0 + 1] * ys[e][2]
                                  + fr[f0 + 2] * ys[e][3];
                    acc += w * d;
                }
            }
        }
        __syncthreads();   // before next chunk overwrites LDS
    }

    // ---- write z (proj 1/8 folded in wbuf; agg 1/sqrt(16) here) ----
    const float sZ = 0.25f;
    if (t < 128) {
        z[t] = acc * sZ;
    } else if (t < 256) {
        const int u = t - 128;
        z[192 + 0 * 192 + u] = acc3a * sZ;
        z[192 + 1 * 192 + u] = acc3b * sZ;
        z[192 + 2 * 192 + u] = acc3c * sZ;
    } else if (t < 320) {
        const int u = t - 256;
        z[192 + 0 * 192 + 128 + u] = acc3a * sZ;
        z[192 + 1 * 192 + 128 + u] = acc3b * sZ;
        z[192 + 2 * 192 + 128 + u] = acc3c * sZ;
    } else {
        z[128 + (t - 320)] = acc * sZ * 0.5773502691896258f;  // mid0b, 1/sqrt(3)
    }
    __syncthreads();

    // ---- output GEMM + rotation combine ----
    const float sA = 0.07216878364870323f;   // 1/sqrt(192)
    const float cR = 0.92387953251128674f;   // cos(pi/8)
    const float sR = 0.38268343236508978f;   // sin(pi/8)

    if (t < 128) {
        float conv = 0.f;
        const float4* z4 = (const float4*)z;
#pragma unroll 8
        for (int q = 0; q < 48; ++q) {
            const float4 zz = z4[q];
            conv += zz.x * Wo0[(4 * q + 0) * 128 + t];
            conv += zz.y * Wo0[(4 * q + 1) * 128 + t];
            conv += zz.z * Wo0[(4 * q + 2) * 128 + t];
            conv += zz.w * Wo0[(4 * q + 3) * 128 + t];
        }
        const float sv = self_tbl[(size_t)node * FEAT_W + t];
        out[(size_t)node * FEAT_W + t] = cR * sv + sR * conv * sA;
    } else if (t < 320) {
        const int idx = t - 128;
        const int i = idx >> 6, u = idx & 63;
        float conv = 0.f;
        const float4* z4 = (const float4*)(z + 192 + i * 192);
#pragma unroll 8
        for (int q = 0; q < 48; ++q) {
            const float4 zz = z4[q];
            conv += zz.x * Wo1[(4 * q + 0) * 64 + u];
            conv += zz.y * Wo1[(4 * q + 1) * 64 + u];
            conv += zz.z * Wo1[(4 * q + 2) * 64 + u];
            conv += zz.w * Wo1[(4 * q + 3) * 64 + u];
        }
        const int col = 128 + u * 3 + i;
        const float sv = self_tbl[(size_t)node * FEAT_W + col];
        out[(size_t)node * FEAT_W + col] = cR * sv + sR * conv * sA;
    }
}

extern "C" void kernel_launch(void* const* d_in, const int* in_sizes, int n_in,
                              void* d_out, int out_size, void* d_ws, size_t ws_size,
                              hipStream_t stream) {
    const float* node_input = (const float*)d_in[0];
    const float* edge_attr  = (const float*)d_in[1];
    const float* esa        = (const float*)d_in[2];
    const float* Wa0  = (const float*)d_in[3];
    const float* Wa1  = (const float*)d_in[4];
    const float* Wb0  = (const float*)d_in[5];
    const float* Wb1  = (const float*)d_in[6];
    const float* M1   = (const float*)d_in[7];
    const float* M2   = (const float*)d_in[8];
    const float* Wtp0 = (const float*)d_in[9];
    const float* Wtp1 = (const float*)d_in[10];
    const float* Wtp2 = (const float*)d_in[11];
    const float* Wtp3 = (const float*)d_in[12];
    const float* Wo0  = (const float*)d_in[13];
    const float* Wo1  = (const float*)d_in[14];
    const int* edge_src = (const int*)d_in[15];
    const int* edge_dst = (const int*)d_in[16];
    float* out = (float*)d_out;

    // ws usage: 68 MB (proven) + 123 MB f16 wbuf = ~191 MB (proven R11)
    float*  feat_tbl = (float*)d_ws;                              // 10000*320
    float*  self_tbl = feat_tbl + (size_t)N_NODES * FEAT_W;       // 10000*320
    float*  h2buf    = self_tbl + (size_t)N_NODES * FEAT_W;       // 160000*64
    int*    counts   = (int*)(h2buf + (size_t)N_EDGES * 64);      // 10000
    int*    offsets  = counts + N_NODES;                          // 10001
    int*    cursor   = offsets + N_NODES + 1;                     // 10000
    int*    elist    = cursor + N_NODES;                          // 160000
    __half* wbuf     = (__half*)(elist + N_EDGES);                // 160000*384 f16

    hipMemsetAsync(counts, 0, sizeof(int) * N_NODES, stream);

    node_transform<<<N_NODES / 8, 256, 0, stream>>>(node_input, Wa0, Wa1, Wb0, Wb1,
                                                    feat_tbl, self_tbl);
    mlp_kernel<<<N_EDGES / 4, 256, 0, stream>>>(esa, M1, M2, edge_dst, h2buf, counts);
    scan_kernel<<<1, 1024, 0, stream>>>(counts, offsets, cursor);
    fill_kernel<<<N_EDGES / 256, 256, 0, stream>>>(edge_dst, cursor, elist);
    wproj_kernel<<<N_EDGES / WPE, 256, 0, stream>>>(
        elist, h2buf, Wtp0, Wtp1, Wtp2, Wtp3, wbuf);
    gather_kernel<<<N_NODES, 384, 0, stream>>>(offsets, elist, edge_src,
                                               edge_attr, wbuf, feat_tbl, self_tbl,
                                               Wo0, Wo1, out);
}

// Round 13
// 414.939 us; speedup vs baseline: 2.7105x; 1.1124x over previous
//
#include <hip/hip_runtime.h>
#include <hip/hip_bf16.h>
#include <hip/hip_fp16.h>

#define N_NODES 10000
#define N_EDGES 160000
#define FEAT_W 320
#define CHUNK 32
#define WPE 64    // edges per wproj block

typedef _Float16 half8 __attribute__((ext_vector_type(8)));
typedef float f32x4 __attribute__((ext_vector_type(4)));

__device__ __forceinline__ float gelu_tanh(float x) {
    float x3 = x * x * x;
    float t = tanhf(0.7978845608028654f * (x + 0.044715f * x3));
    return 0.5f * x * (1.0f + t);
}

// ---------------- Kernel 1: node transforms, 8 nodes/block, fused feat+self -
// xT[v][n] transposed LDS tile: per v, x for 8 nodes read as 2 ds_read_b128.
// feat_tbl / self_tbl rows: [0..128) = mul0 part, [128..320) = mul1 as u*3+i
__global__ __launch_bounds__(320) void node_transform(
    const float* __restrict__ node_input,
    const float* __restrict__ Wa0, const float* __restrict__ Wa1,
    const float* __restrict__ Wb0, const float* __restrict__ Wb1,
    float* __restrict__ feat_tbl, float* __restrict__ self_tbl)
{
    __shared__ __align__(16) float xT[FEAT_W][8];   // 10.24 KB
    const int node0 = blockIdx.x * 8;
    const int t = threadIdx.x;                      // 0..319 = output col
    for (int q = t; q < 640; q += 320) {            // 8 rows x 80 float4
        const int n = q / 80, c4 = q - n * 80;
        const float4 v = ((const float4*)(node_input + (size_t)(node0 + n) * FEAT_W))[c4];
        xT[c4 * 4 + 0][n] = v.x; xT[c4 * 4 + 1][n] = v.y;
        xT[c4 * 4 + 2][n] = v.z; xT[c4 * 4 + 3][n] = v.w;
    }
    __syncthreads();

    float accf[8] = {0,0,0,0,0,0,0,0}, accs[8] = {0,0,0,0,0,0,0,0};
    float scale;
    if (t < 128) {
        for (int v = 0; v < 128; ++v) {
            const float wa = Wa0[v * 128 + t];
            const float wb = Wb0[v * 128 + t];
            const float4 xa = *(const float4*)&xT[v][0];
            const float4 xb = *(const float4*)&xT[v][4];
            accf[0] += xa.x * wa; accf[1] += xa.y * wa; accf[2] += xa.z * wa; accf[3] += xa.w * wa;
            accf[4] += xb.x * wa; accf[5] += xb.y * wa; accf[6] += xb.z * wa; accf[7] += xb.w * wa;
            accs[0] += xa.x * wb; accs[1] += xa.y * wb; accs[2] += xa.z * wb; accs[3] += xa.w * wb;
            accs[4] += xb.x * wb; accs[5] += xb.y * wb; accs[6] += xb.z * wb; accs[7] += xb.w * wb;
        }
        scale = 0.08838834764831845f;               // 1/sqrt(128)
    } else {
        const int r = t - 128, u = r / 3, i = r - 3 * u;
        for (int v = 0; v < 64; ++v) {
            const float wa = Wa1[v * 64 + u];
            const float wb = Wb1[v * 64 + u];
            const int row = 128 + v * 3 + i;
            const float4 xa = *(const float4*)&xT[row][0];
            const float4 xb = *(const float4*)&xT[row][4];
            accf[0] += xa.x * wa; accf[1] += xa.y * wa; accf[2] += xa.z * wa; accf[3] += xa.w * wa;
            accf[4] += xb.x * wa; accf[5] += xb.y * wa; accf[6] += xb.z * wa; accf[7] += xb.w * wa;
            accs[0] += xa.x * wb; accs[1] += xa.y * wb; accs[2] += xa.z * wb; accs[3] += xa.w * wb;
            accs[4] += xb.x * wb; accs[5] += xb.y * wb; accs[6] += xb.z * wb; accs[7] += xb.w * wb;
        }
        scale = 0.125f;                             // 1/sqrt(64)
    }
#pragma unroll
    for (int n = 0; n < 8; ++n) {
        feat_tbl[(size_t)(node0 + n) * FEAT_W + t] = accf[n] * scale;
        self_tbl[(size_t)(node0 + n) * FEAT_W + t] = accs[n] * scale;
    }
}

// ---------------- Kernel 2: per-edge MLP -> h2 (+ degree count fused) -------
__global__ __launch_bounds__(256) void mlp_kernel(
    const float* __restrict__ esa,   // (E,8)
    const float* __restrict__ M1,    // (8,64)
    const float* __restrict__ M2,    // (64,64)
    const int* __restrict__ edge_dst,
    float* __restrict__ h2buf,       // (E,64)
    int* __restrict__ counts)
{
    __shared__ __align__(16) float sh[4][64];
    const int wave = threadIdx.x >> 6;
    const int lane = threadIdx.x & 63;
    const int e = blockIdx.x * 4 + wave;   // N_EDGES % 4 == 0

    if (lane == 0) atomicAdd(&counts[edge_dst[e]], 1);

    const float4 e0 = ((const float4*)(esa + (size_t)e * 8))[0];
    const float4 e1 = ((const float4*)(esa + (size_t)e * 8))[1];
    float h = e0.x * M1[0 * 64 + lane] + e0.y * M1[1 * 64 + lane]
            + e0.z * M1[2 * 64 + lane] + e0.w * M1[3 * 64 + lane]
            + e1.x * M1[4 * 64 + lane] + e1.y * M1[5 * 64 + lane]
            + e1.z * M1[6 * 64 + lane] + e1.w * M1[7 * 64 + lane];
    h = gelu_tanh(h * 0.35355339059327373f);   // 1/sqrt(8)
    sh[wave][lane] = h;
    __syncthreads();

    float h2 = 0.f;
    const float4* shp = (const float4*)sh[wave];
#pragma unroll
    for (int q = 0; q < 16; ++q) {
        const float4 s = shp[q];
        h2 += s.x * M2[(4 * q + 0) * 64 + lane];
        h2 += s.y * M2[(4 * q + 1) * 64 + lane];
        h2 += s.z * M2[(4 * q + 2) * 64 + lane];
        h2 += s.w * M2[(4 * q + 3) * 64 + lane];
    }
    h2 = gelu_tanh(h2 * 0.125f);               // 1/sqrt(64)
    h2buf[(size_t)e * 64 + lane] = h2;
}

// ---------------- CSR build -------------------------------------------------
__global__ __launch_bounds__(1024) void scan_kernel(
    const int* __restrict__ counts, int* __restrict__ offsets, int* __restrict__ cursor)
{
    __shared__ int wsum[16];
    const int wid = threadIdx.x >> 6, lane = threadIdx.x & 63;
    int base = 0;
    for (int c = 0; c < 10; ++c) {            // 10*1024 >= 10000
        const int i = c * 1024 + threadIdx.x;
        const int v = (i < N_NODES) ? counts[i] : 0;
        int x = v;
#pragma unroll
        for (int off = 1; off < 64; off <<= 1) {
            int y = __shfl_up(x, off, 64);
            if (lane >= off) x += y;
        }
        if (lane == 63) wsum[wid] = x;
        __syncthreads();
        if (threadIdx.x < 16) {
            int s = wsum[threadIdx.x];
#pragma unroll
            for (int off = 1; off < 16; off <<= 1) {
                int y = __shfl_up(s, off, 64);
                if ((int)threadIdx.x >= off) s += y;
            }
            wsum[threadIdx.x] = s;
        }
        __syncthreads();
        const int waveoff = (wid == 0) ? 0 : wsum[wid - 1];
        const int excl = base + waveoff + x - v;
        if (i < N_NODES) { offsets[i] = excl; cursor[i] = excl; }
        const int tot = wsum[15];
        __syncthreads();
        base += tot;
    }
    if (threadIdx.x == 0) offsets[N_NODES] = base;
}

// fill: also emits CSR-permuted src and y4 so gather has no indirection
__global__ void fill_kernel(const int* __restrict__ edge_dst,
                            const int* __restrict__ edge_src,
                            const float* __restrict__ edge_attr,
                            int* __restrict__ cursor, int* __restrict__ elist,
                            int* __restrict__ srcs_csr, float* __restrict__ y4csr) {
    int e = blockIdx.x * 256 + threadIdx.x;
    if (e < N_EDGES) {
        int pos = atomicAdd(&cursor[edge_dst[e]], 1);
        elist[pos] = e;
        srcs_csr[pos] = edge_src[e];
        ((float4*)y4csr)[pos] = ((const float4*)edge_attr)[e];
    }
}

// ---------------- Kernel 3: W-projection via MFMA f16 -----------------------
// grid 2500 blocks x 4 waves. Block = 64 CSR edges x 384 cols; wave owns 96
// cols (6 16-col tiles, B frags in regs), loops 4 edge-groups of 16.
// Layouts (HW-verified, learn_hip m89/m120): A[m=lane&15][k=quad*8+j],
// B[k=quad*8+j][n=lane&15], D col=lane&15 row=quad*4+reg.
__global__ __launch_bounds__(256) void wproj_kernel(
    const int* __restrict__ elist,
    const float* __restrict__ h2buf,       // (E,64)
    const float* __restrict__ Wtp0,        // (64,128)
    const float* __restrict__ Wtp1,        // (64,128)
    const float* __restrict__ Wtp2,        // (64,64)
    const float* __restrict__ Wtp3,        // (64,64)
    __half* __restrict__ wbuf)             // (E,384) f16, CSR order, pre-scaled 1/8
{
    const int wave = threadIdx.x >> 6;
    const int lane = threadIdx.x & 63;
    const int quad = lane >> 4;
    const int n16 = lane & 15;
    const int pbase = blockIdx.x * WPE;    // 2500*64 == N_EDGES
    const int colbase = wave * 96;

    // ---- B fragments for this wave's 6 col-tiles (k = s*32 + quad*8 + j) ----
    half8 bf[6][2];
#pragma unroll
    for (int c = 0; c < 6; ++c) {
        const int col = colbase + c * 16 + n16;
        const float* src; int stride;
        if (col < 128)      { src = Wtp0 + col;         stride = 128; }
        else if (col < 256) { src = Wtp1 + (col - 128); stride = 128; }
        else if (col < 320) { src = Wtp2 + (col - 256); stride = 64;  }
        else                { src = Wtp3 + (col - 320); stride = 64;  }
#pragma unroll
        for (int s = 0; s < 2; ++s)
#pragma unroll
            for (int j = 0; j < 8; ++j)
                bf[c][s][j] = (_Float16)src[(s * 32 + quad * 8 + j) * stride];
    }

    // ---- 4 edge groups of 16 ----
    for (int g = 0; g < 4; ++g) {
        const int eid = elist[pbase + g * 16 + n16];   // A row m = n16
        const float* hrow = h2buf + (size_t)eid * 64;
        half8 af[2];
#pragma unroll
        for (int s = 0; s < 2; ++s) {
            const float4 p0 = *(const float4*)(hrow + s * 32 + quad * 8);
            const float4 p1 = *(const float4*)(hrow + s * 32 + quad * 8 + 4);
            af[s][0] = (_Float16)p0.x; af[s][1] = (_Float16)p0.y;
            af[s][2] = (_Float16)p0.z; af[s][3] = (_Float16)p0.w;
            af[s][4] = (_Float16)p1.x; af[s][5] = (_Float16)p1.y;
            af[s][6] = (_Float16)p1.z; af[s][7] = (_Float16)p1.w;
        }
#pragma unroll
        for (int c = 0; c < 6; ++c) {
            f32x4 acc = {0.f, 0.f, 0.f, 0.f};
            acc = __builtin_amdgcn_mfma_f32_16x16x32_f16(af[0], bf[c][0], acc, 0, 0, 0);
            acc = __builtin_amdgcn_mfma_f32_16x16x32_f16(af[1], bf[c][1], acc, 0, 0, 0);
#pragma unroll
            for (int r = 0; r < 4; ++r) {
                const int edge = g * 16 + quad * 4 + r;          // D row
                wbuf[(size_t)(pbase + edge) * 384 + colbase + c * 16 + n16] =
                    (__half)(acc[r] * 0.125f);                   // 1/sqrt(64)
            }
        }
    }
}

// ---------------- Kernel 4: slim gather: TP + out-GEMM ----------------------
// 384 threads/block, one block per node. CSR-ordered inputs: no indirection.
// Mapping (R9-validated): t<128: A mid0a | t<256: B mid1a | t<320: C mid1b | else D mid0b.
// z layout: [0,192)=z0; [192 + i*192 + v)=z1[v][i] planes.
__global__ __launch_bounds__(384) void gather_kernel(
    const int* __restrict__ offsets,
    const int* __restrict__ srcs_csr,
    const float* __restrict__ y4csr,
    const __half* __restrict__ wbuf,       // (E,384) CSR order, pre-scaled 1/8
    const float* __restrict__ feat_tbl,    // (N,320)
    const float* __restrict__ self_tbl,    // (N,320)
    const float* __restrict__ Wo0,         // (192,128)
    const float* __restrict__ Wo1,         // (192,64)
    float* __restrict__ out)               // (N,320)
{
    __shared__ __align__(16) __half wsh[CHUNK * 384];  // 24 KB
    __shared__ float ys[CHUNK][4];
    __shared__ int   srcs[CHUNK];
    __shared__ float z[768];

    const int node = blockIdx.x;
    const int t = threadIdx.x;             // 0..383

    int f0;
    if (t < 128)      f0 = t;
    else if (t < 256) f0 = t - 128;
    else if (t < 320) f0 = 128 + 3 * (t - 256);
    else              f0 = 128 + 3 * (t - 320);

    float acc = 0.f, acc3a = 0.f, acc3b = 0.f, acc3c = 0.f;
    const int beg = offsets[node], end = offsets[node + 1];

    for (int cb = beg; cb < end; cb += CHUNK) {
        const int ne = min(CHUNK, end - cb);
        if (t < ne) {
            srcs[t] = srcs_csr[cb + t];
            ((float4*)ys)[t] = ((const float4*)y4csr)[cb + t];
        }
        // stage w tile (ne*384 f16 = ne*48 float4), coalesced
        for (int q = t; q < ne * 48; q += 384)
            ((float4*)wsh)[q] = ((const float4*)(wbuf + (size_t)cb * 384))[q];
        __syncthreads();

        if (t < 128) {                       // A: mid0a
            for (int e = 0; e < ne; ++e) {
                const float w = __half2float(wsh[e * 384 + t]);
                const float* fr = feat_tbl + (size_t)srcs[e] * FEAT_W;
                acc += w * fr[f0] * ys[e][0];
            }
        } else if (t < 256) {                // B: mid1a
            for (int e = 0; e < ne; ++e) {
                const float w = __half2float(wsh[e * 384 + t]);
                const float* fr = feat_tbl + (size_t)srcs[e] * FEAT_W;
                const float p = w * fr[f0];
                acc3a += p * ys[e][1];
                acc3b += p * ys[e][2];
                acc3c += p * ys[e][3];
            }
        } else if (t < 320) {                // C: mid1b
            for (int e = 0; e < ne; ++e) {
                const float w = __half2float(wsh[e * 384 + t]);
                const float* fr = feat_tbl + (size_t)srcs[e] * FEAT_W;
                const float p = w * ys[e][0];
                acc3a += p * fr[f0];
                acc3b += p * fr[f0 + 1];
                acc3c += p * fr[f0 + 2];
            }
        } else {                             // D: mid0b
            for (int e = 0; e < ne; ++e) {
                const float w = __half2float(wsh[e * 384 + t]);
                const float* fr = feat_tbl + (size_t)srcs[e] * FEAT_W;
                const float d = fr[f0] * ys[e][1] + fr[f0 + 1] * ys[e][2]
                              + fr[f0 + 2] * ys[e][3];
                acc += w * d;
            }
        }
        __syncthreads();   // before next chunk overwrites LDS
    }

    // ---- write z (proj 1/8 folded in wbuf; agg 1/sqrt(16) here) ----
    const float sZ = 0.25f;
    if (t < 128) {
        z[t] = acc * sZ;
    } else if (t < 256) {
        const int u = t - 128;
        z[192 + 0 * 192 + u] = acc3a * sZ;
        z[192 + 1 * 192 + u] = acc3b * sZ;
        z[192 + 2 * 192 + u] = acc3c * sZ;
    } else if (t < 320) {
        const int u = t - 256;
        z[192 + 0 * 192 + 128 + u] = acc3a * sZ;
        z[192 + 1 * 192 + 128 + u] = acc3b * sZ;
        z[192 + 2 * 192 + 128 + u] = acc3c * sZ;
    } else {
        z[128 + (t - 320)] = acc * sZ * 0.5773502691896258f;  // mid0b, 1/sqrt(3)
    }
    __syncthreads();

    // ---- output GEMM + rotation combine ----
    const float sA = 0.07216878364870323f;   // 1/sqrt(192)
    const float cR = 0.92387953251128674f;   // cos(pi/8)
    const float sR = 0.38268343236508978f;   // sin(pi/8)

    if (t < 128) {
        float conv = 0.f;
        const float4* z4 = (const float4*)z;
#pragma unroll 8
        for (int q = 0; q < 48; ++q) {
            const float4 zz = z4[q];
            conv += zz.x * Wo0[(4 * q + 0) * 128 + t];
            conv += zz.y * Wo0[(4 * q + 1) * 128 + t];
            conv += zz.z * Wo0[(4 * q + 2) * 128 + t];
            conv += zz.w * Wo0[(4 * q + 3) * 128 + t];
        }
        const float sv = self_tbl[(size_t)node * FEAT_W + t];
        out[(size_t)node * FEAT_W + t] = cR * sv + sR * conv * sA;
    } else if (t < 320) {
        const int idx = t - 128;
        const int i = idx >> 6, u = idx & 63;
        float conv = 0.f;
        const float4* z4 = (const float4*)(z + 192 + i * 192);
#pragma unroll 8
        for (int q = 0; q < 48; ++q) {
            const float4 zz = z4[q];
            conv += zz.x * Wo1[(4 * q + 0) * 64 + u];
            conv += zz.y * Wo1[(4 * q + 1) * 64 + u];
            conv += zz.z * Wo1[(4 * q + 2) * 64 + u];
            conv += zz.w * Wo1[(4 * q + 3) * 64 + u];
        }
        const int col = 128 + u * 3 + i;
        const float sv = self_tbl[(size_t)node * FEAT_W + col];
        out[(size_t)node * FEAT_W + col] = cR * sv + sR * conv * sA;
    }
}

extern "C" void kernel_launch(void* const* d_in, const int* in_sizes, int n_in,
                              void* d_out, int out_size, void* d_ws, size_t ws_size,
                              hipStream_t stream) {
    const float* node_input = (const float*)d_in[0];
    const float* edge_attr  = (const float*)d_in[1];
    const float* esa        = (const float*)d_in[2];
    const float* Wa0  = (const float*)d_in[3];
    const float* Wa1  = (const float*)d_in[4];
    const float* Wb0  = (const float*)d_in[5];
    const float* Wb1  = (const float*)d_in[6];
    const float* M1   = (const float*)d_in[7];
    const float* M2   = (const float*)d_in[8];
    const float* Wtp0 = (const float*)d_in[9];
    const float* Wtp1 = (const float*)d_in[10];
    const float* Wtp2 = (const float*)d_in[11];
    const float* Wtp3 = (const float*)d_in[12];
    const float* Wo0  = (const float*)d_in[13];
    const float* Wo1  = (const float*)d_in[14];
    const int* edge_src = (const int*)d_in[15];
    const int* edge_dst = (const int*)d_in[16];
    float* out = (float*)d_out;

    // ws usage: ~194 MB (191 proven R11/R12 + srcs_csr 0.64 + y4csr 2.56)
    float*  feat_tbl = (float*)d_ws;                              // 10000*320
    float*  self_tbl = feat_tbl + (size_t)N_NODES * FEAT_W;       // 10000*320
    float*  h2buf    = self_tbl + (size_t)N_NODES * FEAT_W;       // 160000*64
    float*  y4csr    = h2buf + (size_t)N_EDGES * 64;              // 160000*4
    int*    counts   = (int*)(y4csr + (size_t)N_EDGES * 4);       // 10000
    int*    offsets  = counts + N_NODES;                          // 10001
    int*    cursor   = offsets + N_NODES + 1;                     // 10000
    int*    elist    = cursor + N_NODES;                          // 160000
    int*    srcs_csr = elist + N_EDGES;                           // 160000
    __half* wbuf     = (__half*)(srcs_csr + N_EDGES);             // 160000*384 f16

    hipMemsetAsync(counts, 0, sizeof(int) * N_NODES, stream);

    node_transform<<<N_NODES / 8, 320, 0, stream>>>(node_input, Wa0, Wa1, Wb0, Wb1,
                                                    feat_tbl, self_tbl);
    mlp_kernel<<<N_EDGES / 4, 256, 0, stream>>>(esa, M1, M2, edge_dst, h2buf, counts);
    scan_kernel<<<1, 1024, 0, stream>>>(counts, offsets, cursor);
    fill_kernel<<<N_EDGES / 256, 256, 0, stream>>>(edge_dst, edge_src, edge_attr,
                                                   cursor, elist, srcs_csr, y4csr);
    wproj_kernel<<<N_EDGES / WPE, 256, 0, stream>>>(
        elist, h2buf, Wtp0, Wtp1, Wtp2, Wtp3, wbuf);
    gather_kernel<<<N_NODES, 384, 0, stream>>>(offsets, srcs_csr, y4csr, wbuf,
                                               feat_tbl, self_tbl, Wo0, Wo1, out);
}